// Round 7
// baseline (32.665 us; speedup 1.0000x reference)
//
#include <hip/hip_runtime.h>
#include <hip/hip_bf16.h>

typedef float f32x16 __attribute__((ext_vector_type(16)));
typedef float f32x4v __attribute__((ext_vector_type(4)));

#define GLOBAL_AS(p) ((const __attribute__((address_space(1))) void*)(p))
#define LDS_AS(p)    ((__attribute__((address_space(3))) void*)(p))

#define LP 8192
#define D 128
#define TWOEPS 2e-6f
#define CEPS 1.28e-10f   /* 128 * EPS^2 */
#define MARGIN 0.2f
#define NTRI 2080        /* 64*65/2 lower-triangular 128x128 tiles */
#define NBLK 512         /* persistent blocks; blk < 32 take a 5th tile */
#define INV_DENOM 1.4903545e-8f  /* 1 / (8192*8191) */

/* LDS per buffer: A tile 16K | B tile 16K | QW (i-side 1K, j-side 1K) */
#define BUFSZ 34816
#define AOFF 0
#define BOFF 16384
#define QWOFF 32768

// ---------------- Phase A: normalize p rows -> fp8, write qw = (q8, w) -------------
// 4 lanes per row, 16 rows per wave, 1 wave per block, 512 blocks.
// pb[row] = fp8_e4m3(p_hat); qw[row] = { ||fp8(p_hat)||^2 , MARGIN - d_pn(row) }
__global__ __launch_bounds__(64) void rows_kernel(const float* __restrict__ p,
                                                  const float* __restrict__ n,
                                                  char* __restrict__ pb,
                                                  float* __restrict__ qw) {
    const int lane = threadIdx.x;
    const int sub = lane & 3;    // quarter of the row (32 floats)
    const int r = lane >> 2;     // 0..15
    const int row = blockIdx.x * 16 + r;

    const float4* px = (const float4*)(p + (size_t)row * D + sub * 32);
    const float4* nx = (const float4*)(n + sub * 32);  // n row 0 (t=0)
    float4 x[8], y[8];
#pragma unroll
    for (int k = 0; k < 8; ++k) { x[k] = px[k]; y[k] = nx[k]; }

    float ssp = 0.0f, ssn = 0.0f;
#pragma unroll
    for (int k = 0; k < 8; ++k) {
        ssp += fmaf(x[k].x, x[k].x, fmaf(x[k].y, x[k].y,
               fmaf(x[k].z, x[k].z, x[k].w * x[k].w)));
        ssn += fmaf(y[k].x, y[k].x, fmaf(y[k].y, y[k].y,
               fmaf(y[k].z, y[k].z, y[k].w * y[k].w)));
    }
    ssp += __shfl_xor(ssp, 1); ssp += __shfl_xor(ssp, 2);
    ssn += __shfl_xor(ssn, 1); ssn += __shfl_xor(ssn, 2);

    const float invp = 1.0f / fmaxf(sqrtf(ssp), 1e-12f);
    const float invn = 1.0f / fmaxf(sqrtf(ssn), 1e-12f);

    float s = 0.0f, q = 0.0f, dn = 0.0f, sn = 0.0f, qn = 0.0f, q8 = 0.0f;
    int pk8[8];
#pragma unroll
    for (int k = 0; k < 8; ++k) {
        float a0 = x[k].x * invp, a1 = x[k].y * invp,
              a2 = x[k].z * invp, a3 = x[k].w * invp;
        float h0 = y[k].x * invn, h1 = y[k].y * invn,
              h2 = y[k].z * invn, h3 = y[k].w * invn;
        s  += (a0 + a1) + (a2 + a3);
        q  += fmaf(a0, a0, fmaf(a1, a1, fmaf(a2, a2, a3 * a3)));
        dn += fmaf(a0, h0, fmaf(a1, h1, fmaf(a2, h2, a3 * h3)));
        sn += (h0 + h1) + (h2 + h3);
        qn += fmaf(h0, h0, fmaf(h1, h1, fmaf(h2, h2, h3 * h3)));
        int wlo = __builtin_amdgcn_cvt_pk_fp8_f32(a0, a1, 0, false);
        int wfl = __builtin_amdgcn_cvt_pk_fp8_f32(a2, a3, wlo, true);
        pk8[k] = wfl;
        float b0 = __builtin_amdgcn_cvt_f32_fp8(wfl, 0);
        float b1 = __builtin_amdgcn_cvt_f32_fp8(wfl, 1);
        float b2 = __builtin_amdgcn_cvt_f32_fp8(wfl, 2);
        float b3 = __builtin_amdgcn_cvt_f32_fp8(wfl, 3);
        q8 += fmaf(b0, b0, fmaf(b1, b1, fmaf(b2, b2, b3 * b3)));
    }
    // store fp8 row quarter (32 B contiguous per lane)
    char* dst = pb + (size_t)row * 128 + sub * 32;
    ((int4*)dst)[0] = make_int4(pk8[0], pk8[1], pk8[2], pk8[3]);
    ((int4*)dst)[1] = make_int4(pk8[4], pk8[5], pk8[6], pk8[7]);

    // 2-stage reduce over the 4-lane group
#pragma unroll
    for (int m = 1; m < 4; m <<= 1) {
        s += __shfl_xor(s, m);
        q += __shfl_xor(q, m);
        dn += __shfl_xor(dn, m);
        sn += __shfl_xor(sn, m);
        qn += __shfl_xor(qn, m);
        q8 += __shfl_xor(q8, m);
    }
    if (sub == 0) {
        float sq = q + qn - 2.0f * dn + TWOEPS * (s - sn) + CEPS;
        float dpn = sqrtf(fmaxf(sq, 0.0f));
        *(float2*)(qw + (size_t)row * 2) = make_float2(q8, MARGIN - dpn);
    }
}

// ---------------- Phase B: persistent double-buffered triangular pair kernel --------
// Block blk processes tiles {blk, blk+512, ...} (4 or 5). Per tile: stage next
// tile (5 global_load_lds / wave, counted vmcnt(5)) while computing current.
// LDS tiles row-major [128 rows][128 B] with XOR chunk-swizzle (chunk ^= row&7).
// Final: one scaled atomicAdd per block into out[0] (zeroed by host-side memset).
__global__ __launch_bounds__(512, 4) void pair_kernel(const char* __restrict__ pb,
                                                      const float* __restrict__ qw,
                                                      float* __restrict__ out) {
    __shared__ __align__(16) char smem[2 * BUFSZ];  // 69632 B -> 2 blocks/CU
    const int blk = blockIdx.x;
    const int tid = threadIdx.x;
    const int wave = tid >> 6, lane = tid & 63;
    const int nt = (blk < NTRI - 4 * NBLK) ? 5 : 4;  // 32 blocks take a 5th tile

    const int wr = wave >> 2, wc = wave & 3;  // 2x4 waves, 64x32 output each
    const int ln31 = lane & 31;
    const int h = lane >> 5;

    auto decode = [](int b, int& ti, int& tj) {
        int t = (int)((__builtin_amdgcn_sqrtf(8.0f * (float)b + 1.0f) - 1.0f) * 0.5f);
        while ((t + 1) * (t + 2) / 2 <= b) ++t;
        while (t * (t + 1) / 2 > b) --t;
        ti = t;
        tj = b - t * (t + 1) / 2;
    };

    auto stage = [&](int ti, int tj, char* buf) {
        const char* gA = pb + (size_t)ti * 128 * 128;
        const char* gB = pb + (size_t)tj * 128 * 128;
#pragma unroll
        for (int r = 0; r < 2; ++r) {
            int obase = wave * 2048 + r * 1024;  // wave-uniform LDS byte base
            int o = obase + lane * 16;
            int src = o ^ (((o >> 7) & 7) << 4);  // inverse swizzle on global side
            __builtin_amdgcn_global_load_lds(GLOBAL_AS(gA + src),
                                             LDS_AS(buf + AOFF + obase), 16, 0, 0);
            __builtin_amdgcn_global_load_lds(GLOBAL_AS(gB + src),
                                             LDS_AS(buf + BOFF + obase), 16, 0, 0);
        }
        // qw: i-side rows (waves 0-3), j-side rows (waves 4-7); 256 B per wave.
        int side = wave >> 2;
        int chunk = wave & 3;
        const char* gq = (const char*)qw + (size_t)(side ? tj : ti) * 1024 +
                         chunk * 256 + lane * 4;
        __builtin_amdgcn_global_load_lds(GLOBAL_AS(gq),
                                         LDS_AS(buf + QWOFF + side * 1024 + chunk * 256),
                                         4, 0, 0);
    };

    int ti0, tj0;
    decode(blk, ti0, tj0);
    stage(ti0, tj0, smem);  // prologue: tile 0 -> buf 0 (5 loads in flight)
    bool diag_cur = (ti0 == tj0);
    bool diag_nxt = false;

    float la0 = 0.0f, la1 = 0.0f, lb0 = 0.0f, lb1 = 0.0f;

    for (int t = 0; t < nt; ++t) {
        char* cur = smem + (size_t)(t & 1) * BUFSZ;
        char* nxt = smem + (size_t)((t + 1) & 1) * BUFSZ;

        if (t + 1 < nt) {
            int ti, tj;
            decode(blk + (t + 1) * NBLK, ti, tj);
            diag_nxt = (ti == tj);
            stage(ti, tj, nxt);  // 5 more loads -> outstanding <= 10
            asm volatile("s_waitcnt vmcnt(5)" ::: "memory");  // cur's 5 done
        } else {
            asm volatile("s_waitcnt vmcnt(0)" ::: "memory");
        }
        __builtin_amdgcn_s_barrier();        // all waves' cur slices landed
        __builtin_amdgcn_sched_barrier(0);

        const char* lA = cur + AOFF;
        const char* lB = cur + BOFF;
        const float* qwi = (const float*)(cur + QWOFF);
        const float* qwj = (const float*)(cur + QWOFF + 1024);

        f32x16 acc[2] = {};
        __builtin_amdgcn_s_setprio(1);
#pragma unroll
        for (int ks = 0; ks < 8; ++ks) {
            int co = ((ks ^ (ln31 & 7)) << 4) + h * 8;
            long bv = *(const long*)(lB + (wc * 32 + ln31) * 128 + co);
#pragma unroll
            for (int mt = 0; mt < 2; ++mt) {
                long av = *(const long*)(lA + (wr * 64 + mt * 32 + ln31) * 128 + co);
                acc[mt] = __builtin_amdgcn_mfma_f32_32x32x16_fp8_fp8(av, bv, acc[mt],
                                                                     0, 0, 0);
            }
        }
        __builtin_amdgcn_s_setprio(0);

        // Epilogue. C/D 32x32: col = ln31, row = (reg&3) + 8*(reg>>2) + 4*h.
        float2 qwjv = *(const float2*)(qwj + (wc * 32 + ln31) * 2);
        if (diag_cur) {
#pragma unroll
            for (int mt = 0; mt < 2; ++mt)
#pragma unroll
                for (int g = 0; g < 4; ++g) {
                    int rbase = wr * 64 + mt * 32 + 8 * g + 4 * h;
                    f32x4v qw01 = *(const f32x4v*)(qwi + rbase * 2);      // rows +0,+1
                    f32x4v qw23 = *(const f32x4v*)(qwi + rbase * 2 + 4);  // rows +2,+3
                    float qi[4] = {qw01[0], qw01[2], qw23[0], qw23[2]};
                    float wi[4] = {qw01[1], qw01[3], qw23[1], qw23[3]};
#pragma unroll
                    for (int r2 = 0; r2 < 4; ++r2) {
                        float sq = fmaf(-2.0f, acc[mt][g * 4 + r2], qi[r2] + qwjv.x);
                        float d = __builtin_amdgcn_sqrtf(fmaxf(sq, 0.0f));
                        if (mt) la1 += fmaxf(d + wi[r2], 0.0f);
                        else    la0 += fmaxf(d + wi[r2], 0.0f);
                    }
                }
        } else {
#pragma unroll
            for (int mt = 0; mt < 2; ++mt)
#pragma unroll
                for (int g = 0; g < 4; ++g) {
                    int rbase = wr * 64 + mt * 32 + 8 * g + 4 * h;
                    f32x4v qw01 = *(const f32x4v*)(qwi + rbase * 2);
                    f32x4v qw23 = *(const f32x4v*)(qwi + rbase * 2 + 4);
                    float qi[4] = {qw01[0], qw01[2], qw23[0], qw23[2]};
                    float wi[4] = {qw01[1], qw01[3], qw23[1], qw23[3]};
#pragma unroll
                    for (int r2 = 0; r2 < 4; ++r2) {
                        float sq = fmaf(-2.0f, acc[mt][g * 4 + r2], qi[r2] + qwjv.x);
                        float d = __builtin_amdgcn_sqrtf(sq);  // off-diag: sq >= ~0.9
                        if (mt) { la1 += fmaxf(d + wi[r2], 0.0f);
                                  lb1 += fmaxf(d + qwjv.y, 0.0f); }
                        else    { la0 += fmaxf(d + wi[r2], 0.0f);
                                  lb0 += fmaxf(d + qwjv.y, 0.0f); }
                    }
                }
        }
        __builtin_amdgcn_s_barrier();  // reads of cur done before it is re-staged
        diag_cur = diag_nxt;
    }

    float local = (la0 + la1) + (lb0 + lb1);
#pragma unroll
    for (int m = 1; m < 64; m <<= 1) local += __shfl_xor(local, m);
    float* sred = (float*)smem;
    if (lane == 0) sred[wave] = local;
    __syncthreads();
    if (tid == 0) {
        float t0 = (sred[0] + sred[1]) + (sred[2] + sred[3]);
        float t1 = (sred[4] + sred[5]) + (sred[6] + sred[7]);
        atomicAdd(out, (t0 + t1) * INV_DENOM);
    }
}

extern "C" void kernel_launch(void* const* d_in, const int* in_sizes, int n_in,
                              void* d_out, int out_size, void* d_ws, size_t ws_size,
                              hipStream_t stream) {
    const float* p = (const float*)d_in[0];  // [8192,128] f32
    const float* n = (const float*)d_in[1];  // [64,128] f32
    float* out = (float*)d_out;
    char* ws = (char*)d_ws;

    // ws layout
    char*  pb    = ws;                        // 1 MB (8192 x 128 B fp8)
    float* qwarr = (float*)(ws + (1u << 20)); // 64 KB (8192 x float2)

    hipMemsetAsync(out, 0, sizeof(float), stream);  // atomic accumulation target
    hipLaunchKernelGGL(rows_kernel, dim3(LP / 16), dim3(64), 0, stream, p, n, pb, qwarr);
    hipLaunchKernelGGL(pair_kernel, dim3(NBLK), dim3(512), 0, stream, pb, qwarr, out);
}